// Round 2
// baseline (49.608 us; speedup 1.0000x reference)
//
#include <hip/hip_runtime.h>

// LSTM: B=65536, T=9, I=57, H=2 (4H=8 gates), fused single-pass kernel.
// 8 lanes per batch element (one lane per gate). Memory-bound on x (134.5 MB).

#define B_TOTAL 65536
#define T_STEPS 9
#define I_DIM   57

__global__ __launch_bounds__(256, 4)
void lstm_fused(const float* __restrict__ x,
                const float* __restrict__ W_ih,
                const float* __restrict__ W_hh,
                const float* __restrict__ b_ih,
                const float* __restrict__ b_hh,
                const float* __restrict__ fc_w,
                const float* __restrict__ fc_b,
                float* __restrict__ out) {
    const int lane = threadIdx.x & 63;   // lane within wave (wave = 64)
    const int wave = threadIdx.x >> 6;   // wave within block (4 waves)
    const int g    = lane & 7;           // gate index 0..7 (i0,i1,f0,f1,g0,g1,o0,o1)
    const int bg   = lane >> 3;          // batch-in-wave 0..7
    const int b    = blockIdx.x * 32 + wave * 8 + bg;
    if (b >= B_TOTAL) return;

    // Per-lane gate row of W_ih kept in registers (constant indices after unroll).
    float w[I_DIM];
#pragma unroll
    for (int i = 0; i < I_DIM; ++i) w[i] = W_ih[g * I_DIM + i];

    const float whh0 = W_hh[g * 2 + 0];
    const float whh1 = W_hh[g * 2 + 1];
    const float bsum = b_ih[g] + b_hh[g];
    const bool  tanh_gate = ((g >> 1) == 2);   // gates 4,5 use tanh, others sigmoid

    float h0 = 0.f, h1 = 0.f, c0 = 0.f, c1 = 0.f;

    const float* xb = x + (size_t)b * (T_STEPS * I_DIM);

#pragma unroll
    for (int t = 0; t < T_STEPS; ++t) {
        const float* xr = xb + t * I_DIM;
        float acc = bsum + h0 * whh0 + h1 * whh1;
#pragma unroll
        for (int i = 0; i < I_DIM; ++i) acc += xr[i] * w[i];

        // Branch-free activation: sigmoid(v) = 0.5*(1 + tanh(v/2)).
        float y = tanhf(tanh_gate ? acc : 0.5f * acc);
        float a = tanh_gate ? y : (0.5f * y + 0.5f);

        // Gather all 8 gate activations of this batch group (width-8 shuffle).
        float gi0 = __shfl(a, 0, 8);
        float gi1 = __shfl(a, 1, 8);
        float gf0 = __shfl(a, 2, 8);
        float gf1 = __shfl(a, 3, 8);
        float gg0 = __shfl(a, 4, 8);
        float gg1 = __shfl(a, 5, 8);
        float go0 = __shfl(a, 6, 8);
        float go1 = __shfl(a, 7, 8);

        c0 = gf0 * c0 + gi0 * gg0;
        c1 = gf1 * c1 + gi1 * gg1;
        h0 = go0 * tanhf(c0);
        h1 = go1 * tanhf(c1);
    }

    if (g == 0) {
        out[b] = h0 * fc_w[0] + h1 * fc_w[1] + fc_b[0];
    }
}

extern "C" void kernel_launch(void* const* d_in, const int* in_sizes, int n_in,
                              void* d_out, int out_size, void* d_ws, size_t ws_size,
                              hipStream_t stream) {
    const float* x    = (const float*)d_in[0];
    const float* W_ih = (const float*)d_in[1];
    const float* W_hh = (const float*)d_in[2];
    const float* b_ih = (const float*)d_in[3];
    const float* b_hh = (const float*)d_in[4];
    const float* fc_w = (const float*)d_in[5];
    const float* fc_b = (const float*)d_in[6];
    float* out = (float*)d_out;

    // 32 batches per 256-thread block (8 lanes per batch) -> 2048 blocks.
    lstm_fused<<<dim3(B_TOTAL / 32), dim3(256), 0, stream>>>(
        x, W_ih, W_hh, b_ih, b_hh, fc_w, fc_b, out);
}

// Round 3
// 42.870 us; speedup vs baseline: 1.1572x; 1.1572x over previous
//
#include <hip/hip_runtime.h>

// LSTM: B=65536, T=9, I=57, H=2 (4H=8 gates), fused single-pass kernel.
// 8 lanes per batch element. Cooperative dot: lane j loads x-slice {j, j+8,..},
// holds rotated weight slices, rotate-reduce puts gate j's sum on lane j.

#define B_TOTAL 65536
#define T_STEPS 9
#define I_DIM   57

__global__ __launch_bounds__(256, 4)
void lstm_fused(const float* __restrict__ x,
                const float* __restrict__ W_ih,
                const float* __restrict__ W_hh,
                const float* __restrict__ b_ih,
                const float* __restrict__ b_hh,
                const float* __restrict__ fc_w,
                const float* __restrict__ fc_b,
                float* __restrict__ out) {
    const int lane = threadIdx.x & 63;   // lane within wave (wave = 64)
    const int wave = threadIdx.x >> 6;   // wave within block (4 waves)
    const int j    = lane & 7;           // lane within sub-group (gate owner + i-slice owner)
    const int sg   = lane >> 3;          // sub-group (batch) within wave, 0..7
    const int b    = blockIdx.x * 32 + wave * 8 + sg;
    if (b >= B_TOTAL) return;

    // Rotated weight slices: acc[d] accumulates gate (j+d)&7 over i-slice {j+8k}.
    // wrot[d][7] pairs with the broadcast load of x[56]; only lane j==0 contributes.
    float wrot[8][8];
#pragma unroll
    for (int d = 0; d < 8; ++d) {
        const int g = (j + d) & 7;
        const float* wr = W_ih + g * I_DIM;
#pragma unroll
        for (int k = 0; k < 7; ++k) wrot[d][k] = wr[j + 8 * k];
        wrot[d][7] = (j == 0) ? wr[56] : 0.0f;
    }

    // Per-lane gate parameters (this lane finalizes gate j).
    const float whh0 = W_hh[j * 2 + 0];
    const float whh1 = W_hh[j * 2 + 1];
    const float bsum = b_ih[j] + b_hh[j];
    const bool  tanh_gate = ((j >> 1) == 2);   // gates 4,5 use tanh, others sigmoid

    float h0 = 0.f, h1 = 0.f, c0 = 0.f, c1 = 0.f;

    const float* xb = x + (size_t)b * (T_STEPS * I_DIM);

#pragma unroll
    for (int t = 0; t < T_STEPS; ++t) {
        const float* xr = xb + t * I_DIM;

        // Coalesced slice loads: lanes j=0..7 read adjacent dwords per k.
        float xv[8];
#pragma unroll
        for (int k = 0; k < 7; ++k) xv[k] = xr[j + 8 * k];
        xv[7] = xr[56];   // broadcast (same addr for all 8 lanes of the group)

        // Diagonal partial dots: acc[d] = partial for gate (j+d)&7.
        float acc[8];
#pragma unroll
        for (int d = 0; d < 8; ++d) {
            float a = wrot[d][0] * xv[0];
#pragma unroll
            for (int k = 1; k < 8; ++k) a += wrot[d][k] * xv[k];
            acc[d] = a;
        }

        // Rotate-reduce: lane j gathers gate j's partial from lane (j-d)&7.
        float tot = acc[0];
#pragma unroll
        for (int d = 1; d < 8; ++d) tot += __shfl(acc[d], (j - d) & 7, 8);

        tot += bsum + h0 * whh0 + h1 * whh1;

        // Branch-free activation: sigmoid(v) = 0.5*(1 + tanh(v/2)).
        float y = tanhf(tanh_gate ? tot : 0.5f * tot);
        float a = tanh_gate ? y : (0.5f * y + 0.5f);

        // Gather all 8 gate activations of this batch group (width-8 shuffle).
        float gi0 = __shfl(a, 0, 8);
        float gi1 = __shfl(a, 1, 8);
        float gf0 = __shfl(a, 2, 8);
        float gf1 = __shfl(a, 3, 8);
        float gg0 = __shfl(a, 4, 8);
        float gg1 = __shfl(a, 5, 8);
        float go0 = __shfl(a, 6, 8);
        float go1 = __shfl(a, 7, 8);

        c0 = gf0 * c0 + gi0 * gg0;
        c1 = gf1 * c1 + gi1 * gg1;
        h0 = go0 * tanhf(c0);
        h1 = go1 * tanhf(c1);
    }

    if (j == 0) {
        out[b] = h0 * fc_w[0] + h1 * fc_w[1] + fc_b[0];
    }
}

extern "C" void kernel_launch(void* const* d_in, const int* in_sizes, int n_in,
                              void* d_out, int out_size, void* d_ws, size_t ws_size,
                              hipStream_t stream) {
    const float* x    = (const float*)d_in[0];
    const float* W_ih = (const float*)d_in[1];
    const float* W_hh = (const float*)d_in[2];
    const float* b_ih = (const float*)d_in[3];
    const float* b_hh = (const float*)d_in[4];
    const float* fc_w = (const float*)d_in[5];
    const float* fc_b = (const float*)d_in[6];
    float* out = (float*)d_out;

    // 32 batches per 256-thread block (8 lanes per batch) -> 2048 blocks.
    lstm_fused<<<dim3(B_TOTAL / 32), dim3(256), 0, stream>>>(
        x, W_ih, W_hh, b_ih, b_hh, fc_w, fc_b, out);
}

// Round 4
// 42.850 us; speedup vs baseline: 1.1577x; 1.0005x over previous
//
#include <hip/hip_runtime.h>

// LSTM: B=65536, T=9, I=57, H=2 (4H=8 gates), fused single-pass kernel.
// 8 lanes per batch element. Cooperative dot: lane j loads x-slice {j, j+8,..},
// holds rotated weight slices, rotate-reduce puts gate j's sum on lane j.
// amdgpu_waves_per_eu(4,4): pin occupancy so the allocator keeps the 64
// loop-invariant weights register-resident instead of re-loading per timestep
// (R3 showed VGPR_Count=52 -> weights were rematerialized; VMEM-issue-bound).

#define B_TOTAL 65536
#define T_STEPS 9
#define I_DIM   57

__global__ __launch_bounds__(256)
__attribute__((amdgpu_waves_per_eu(4, 4)))
void lstm_fused(const float* __restrict__ x,
                const float* __restrict__ W_ih,
                const float* __restrict__ W_hh,
                const float* __restrict__ b_ih,
                const float* __restrict__ b_hh,
                const float* __restrict__ fc_w,
                const float* __restrict__ fc_b,
                float* __restrict__ out) {
    const int lane = threadIdx.x & 63;   // lane within wave (wave = 64)
    const int wave = threadIdx.x >> 6;   // wave within block (4 waves)
    const int j    = lane & 7;           // lane within sub-group (gate owner + i-slice owner)
    const int sg   = lane >> 3;          // sub-group (batch) within wave, 0..7
    const int b    = blockIdx.x * 32 + wave * 8 + sg;
    if (b >= B_TOTAL) return;

    // Rotated weight slices: acc[d] accumulates gate (j+d)&7 over i-slice {j+8k}.
    // wrot[d][7] pairs with the broadcast load of x[56]; only lane j==0 contributes.
    float wrot[8][8];
#pragma unroll
    for (int d = 0; d < 8; ++d) {
        const int g = (j + d) & 7;
        const float* wr = W_ih + g * I_DIM;
#pragma unroll
        for (int k = 0; k < 7; ++k) wrot[d][k] = wr[j + 8 * k];
        wrot[d][7] = (j == 0) ? wr[56] : 0.0f;
    }

    // Per-lane gate parameters (this lane finalizes gate j).
    const float whh0 = W_hh[j * 2 + 0];
    const float whh1 = W_hh[j * 2 + 1];
    const float bsum = b_ih[j] + b_hh[j];
    const bool  tanh_gate = ((j >> 1) == 2);   // gates 4,5 use tanh, others sigmoid

    float h0 = 0.f, h1 = 0.f, c0 = 0.f, c1 = 0.f;

    const float* xb = x + (size_t)b * (T_STEPS * I_DIM);

#pragma unroll
    for (int t = 0; t < T_STEPS; ++t) {
        const float* xr = xb + t * I_DIM;

        // Coalesced slice loads: lanes j=0..7 read adjacent dwords per k.
        float xv[8];
#pragma unroll
        for (int k = 0; k < 7; ++k) xv[k] = xr[j + 8 * k];
        xv[7] = xr[56];   // broadcast (same addr for all 8 lanes of the group)

        // Diagonal partial dots: acc[d] = partial for gate (j+d)&7.
        float acc[8];
#pragma unroll
        for (int d = 0; d < 8; ++d) {
            float a = wrot[d][0] * xv[0];
#pragma unroll
            for (int k = 1; k < 8; ++k) a += wrot[d][k] * xv[k];
            acc[d] = a;
        }

        // Rotate-reduce: lane j gathers gate j's partial from lane (j-d)&7.
        float tot = acc[0];
#pragma unroll
        for (int d = 1; d < 8; ++d) tot += __shfl(acc[d], (j - d) & 7, 8);

        tot += bsum + h0 * whh0 + h1 * whh1;

        // Branch-free activation: sigmoid(v) = 0.5*(1 + tanh(v/2)).
        float y = tanhf(tanh_gate ? tot : 0.5f * tot);
        float a = tanh_gate ? y : (0.5f * y + 0.5f);

        // Gather all 8 gate activations of this batch group (width-8 shuffle).
        float gi0 = __shfl(a, 0, 8);
        float gi1 = __shfl(a, 1, 8);
        float gf0 = __shfl(a, 2, 8);
        float gf1 = __shfl(a, 3, 8);
        float gg0 = __shfl(a, 4, 8);
        float gg1 = __shfl(a, 5, 8);
        float go0 = __shfl(a, 6, 8);
        float go1 = __shfl(a, 7, 8);

        c0 = gf0 * c0 + gi0 * gg0;
        c1 = gf1 * c1 + gi1 * gg1;
        h0 = go0 * tanhf(c0);
        h1 = go1 * tanhf(c1);
    }

    if (j == 0) {
        out[b] = h0 * fc_w[0] + h1 * fc_w[1] + fc_b[0];
    }
}

extern "C" void kernel_launch(void* const* d_in, const int* in_sizes, int n_in,
                              void* d_out, int out_size, void* d_ws, size_t ws_size,
                              hipStream_t stream) {
    const float* x    = (const float*)d_in[0];
    const float* W_ih = (const float*)d_in[1];
    const float* W_hh = (const float*)d_in[2];
    const float* b_ih = (const float*)d_in[3];
    const float* b_hh = (const float*)d_in[4];
    const float* fc_w = (const float*)d_in[5];
    const float* fc_b = (const float*)d_in[6];
    float* out = (float*)d_out;

    // 32 batches per 256-thread block (8 lanes per batch) -> 2048 blocks.
    lstm_fused<<<dim3(B_TOTAL / 32), dim3(256), 0, stream>>>(
        x, W_ih, W_hh, b_ih, b_hh, fc_w, fc_b, out);
}